// Round 13
// baseline (189.008 us; speedup 1.0000x reference)
//
#include <hip/hip_runtime.h>
#include <stdint.h>

#define TOKENS 16384
#define DDIM   1024
#define NEXP   64
#define NCOL   128              // 64 gate + 64 noise cols
#define TB     32               // tokens per block
#define NBLK   (TOKENS / TB)    // 512 blocks
#define NCH    (DDIM / 32)      // 32 k-chunks of 32
#define NTILE  8                // 8 col-tiles of 16
#define CPP    8                // chunks per K-phase (4 phases x 256 k)

typedef __attribute__((ext_vector_type(8))) short bf16x8;  // 8 bf16 = 4 VGPR
typedef __attribute__((ext_vector_type(4))) float f32x4;

// -------- device-global scratch --------
// W pre-split, fragment order: g_wf[p][ct][kc][lane][j] =
//   W_p[ct*16+(lane&15)][kc*32+(lane>>4)*8+j]        (768 KB, L2-resident)
__device__ ushort g_wf[3][NTILE][NCH][64][8];
__device__ float g_ps[NEXP];          // sum of clean router probs per expert
__device__ float g_cnt[NEXP];         // top-2 counts per expert
__device__ float g_spa[1];            // sum of softplus
__device__ unsigned g_wdone;          // stage-A (W-split) completion counter
__device__ unsigned g_done;           // epilogue completion counter

// ---------------- bf16 3-way split (x = h + m + l + O(2^-27 x)) ----------------
__device__ inline ushort bf16rne(float f) {
  uint32_t u = __float_as_uint(f);
  return (ushort)((u + 0x7fffu + ((u >> 16) & 1u)) >> 16);
}
__device__ inline float bf16tof(ushort h) {
  return __uint_as_float(((uint32_t)h) << 16);
}
__device__ inline void split3(float v, ushort& h, ushort& m, ushort& l) {
  h = bf16rne(v);
  float r1 = v - bf16tof(h);     // exact
  m = bf16rne(r1);
  float r2 = r1 - bf16tof(m);    // exact
  l = bf16rne(r2);
}

// ---------------- JAX threefry2x32 (20 rounds) ----------------
struct U2 { uint32_t a, b; };

__host__ __device__ constexpr U2 tf2x32(uint32_t k0, uint32_t k1,
                                        uint32_t x0, uint32_t x1) {
  uint32_t ks[3] = {k0, k1, k0 ^ k1 ^ 0x1BD11BDAu};
  const uint32_t rot[2][4] = {{13u, 15u, 26u, 6u}, {17u, 29u, 16u, 24u}};
  x0 += ks[0]; x1 += ks[1];
  for (int d = 0; d < 5; ++d) {
    for (int j = 0; j < 4; ++j) {
      uint32_t r = rot[d & 1][j];
      x0 += x1;
      x1 = (x1 << r) | (x1 >> (32u - r));
      x1 ^= x0;
    }
    x0 += ks[(d + 1) % 3];
    x1 += ks[(d + 2) % 3] + (uint32_t)(d + 1);
  }
  return U2{x0, x1};
}

// JAX >=0.5 partitionable threefry: bits[i] = xor-fold(tf(key, (0, i)))
__device__ inline uint32_t noise_bits(uint32_t i) {
  constexpr U2 NK = tf2x32(0u, 0u, 0u, 12345u);   // fold_in(key(0), 12345)
  U2 o = tf2x32(NK.a, NK.b, 0u, i);
  return o.a ^ o.b;
}

// XLA ErfInv32 (Giles polynomial)
__device__ inline float xla_erfinv(float x) {
  float w = -log1pf(-x * x);
  float p;
  if (w < 5.0f) {
    w = w - 2.5f;
    p = 2.81022636e-08f;
    p = 3.43273939e-07f + p * w;
    p = -3.5233877e-06f + p * w;
    p = -4.39150654e-06f + p * w;
    p = 0.00021858087f + p * w;
    p = -0.00125372503f + p * w;
    p = -0.00417768164f + p * w;
    p = 0.246640727f + p * w;
    p = 1.50140941f + p * w;
  } else {
    w = sqrtf(w) - 3.0f;
    p = -0.000200214257f;
    p = 0.000100950558f + p * w;
    p = 0.00134934322f + p * w;
    p = -0.00367342844f + p * w;
    p = 0.00573950773f + p * w;
    p = -0.0076224613f + p * w;
    p = 0.00943887047f + p * w;
    p = 1.00167406f + p * w;
    p = 2.83297682f + p * w;
  }
  return p * x;
}

__device__ inline float noise_normal(uint32_t i) {
  uint32_t bits = noise_bits(i);
  float f = __uint_as_float((bits >> 9) | 0x3f800000u) - 1.0f;  // [0,1)
  float u = f * 2.0f + (-0.99999994f);
  u = fmaxf(u, -0.99999994f);
  return 1.41421356237f * xla_erfinv(u);
}

__device__ inline float softplus_ref(float x) {
  return fmaxf(x, 0.0f) + log1pf(expf(-fabsf(x)));
}

// ---------------- wave(64) primitives ----------------
__device__ inline float wave_max64(float v) {
  #pragma unroll
  for (int off = 32; off; off >>= 1) v = fmaxf(v, __shfl_xor(v, off, 64));
  return v;
}
__device__ inline float wave_sum64(float v) {
  #pragma unroll
  for (int off = 32; off; off >>= 1) v += __shfl_xor(v, off, 64);
  return v;
}
__device__ inline void wave_argmax64(float v, int idx, float& mv, int& mi) {
  float bv = v; int bi = idx;
  #pragma unroll
  for (int off = 32; off; off >>= 1) {
    float ov = __shfl_xor(bv, off, 64);
    int   oi = __shfl_xor(bi, off, 64);
    if (ov > bv || (ov == bv && oi < bi)) { bv = ov; bi = oi; }
  }
  mv = bv; mi = bi;
}

// ---------------- single fused kernel ----------------
// Stage A: blocks 0..255 split W into fragment-ordered bf16 h/m/l (64 lanes
//   each, same math as the old wsplit_kernel); block 0 zeroes accumulators.
//   Each producer: __threadfence + release-increment g_wdone.
// Spin barrier: all 512 blocks wait for g_wdone==256 (acquire + fence).
//   Deadlock-free: producers are self-sufficient, dispatched first, and
//   capacity (2-3 blocks/CU x 256 CU >= 512) makes all blocks co-resident.
// Stage B: r12's GEMM + epilogue, byte-identical -> bit-identical logits.
// Stage C: last-done block (g_done, r3-proven pattern) finalizes the two
//   scalars and resets both counters for graph replay.
__global__ __launch_bounds__(1024, 8)
void NoisyTopKRouter_57621281243491_kernel(
    const float* __restrict__ x, const float* __restrict__ wg,
    const float* __restrict__ wn, float* __restrict__ out) {
  __shared__ ushort ldsA[3][2][CPP][64][8];     // 49.2 KB; epilogue aliases it

  const int tid  = threadIdx.x;
  const int bid  = blockIdx.x;
  const int w    = tid >> 6;          // wave 0..15
  const int lane = tid & 63;
  const int tg   = w & 1;             // token group
  const int ct   = w >> 1;            // col tile (pairs share -> L1 B reuse)
  const int tok0 = bid * TB;

  char* LA = (char*)&ldsA[0][0][0][0][0];

  // ---- stage A: W-split (blocks 0..255, first 64 lanes) ----
  if (bid < NTILE * NCH) {
    if (tid < 64) {
      const int act  = bid >> 5;           // col tile 0..7
      const int akc  = bid & 31;           // k-chunk 0..31
      const int col  = act * 16 + (tid & 15);
      const int koff = akc * 32 + (tid >> 4) * 8;
      const float* src = (col < NEXP) ? (wg + (size_t)col * DDIM)
                                      : (wn + (size_t)(col - NEXP) * DDIM);
      const float4 v0 = *(const float4*)&src[koff];
      const float4 v1 = *(const float4*)&src[koff + 4];
      const float av[8] = {v0.x, v0.y, v0.z, v0.w, v1.x, v1.y, v1.z, v1.w};
      union BF8 { bf16x8 v; ushort u[8]; };
      BF8 H, M, L;
      #pragma unroll
      for (int j = 0; j < 8; ++j) {
        ushort h, m, l;
        split3(av[j], h, m, l);
        H.u[j] = h; M.u[j] = m; L.u[j] = l;
      }
      *(bf16x8*)&g_wf[0][act][akc][tid][0] = H.v;
      *(bf16x8*)&g_wf[1][act][akc][tid][0] = M.v;
      *(bf16x8*)&g_wf[2][act][akc][tid][0] = L.v;
    }
    if (bid == 0) {   // zero loss accumulators (ordered via the release chain)
      if (tid >= 64 && tid < 128) { g_ps[tid - 64] = 0.0f; g_cnt[tid - 64] = 0.0f; }
      if (tid == 128) g_spa[0] = 0.0f;
    }
    __syncthreads();
    if (tid == 0) {
      __threadfence();   // publish g_wf (and block 0's zeroes) device-wide
      __hip_atomic_fetch_add(&g_wdone, 1u, __ATOMIC_RELEASE,
                             __HIP_MEMORY_SCOPE_AGENT);
    }
  }

  // ---- spin barrier: wait for all 256 producer blocks ----
  if (tid == 0) {
    while (__hip_atomic_load(&g_wdone, __ATOMIC_ACQUIRE,
                             __HIP_MEMORY_SCOPE_AGENT) < (unsigned)(NTILE * NCH))
      __builtin_amdgcn_s_sleep(2);
    __threadfence();   // acquire side: invalidate caches before g_wf reads
  }
  __syncthreads();

  // ---- stage B: GEMM (byte-identical to r12) ----
  const int srow = tid >> 5;          // 0..31 token row
  const int skq  = tid & 31;          // 0..31: fragment (chunk, k-oct) in phase
  const int stg  = srow >> 4;         // token group
  const int sfr  = srow & 15;         // fragment row
  const int sc   = skq >> 2;          // chunk within phase (0..7)
  const int ss   = skq & 3;           // k-oct within chunk
  const int so   = (sc * 1024 + ss * 256 + sfr * 16) ^ ((skq & 15) << 4);
  const float* sx = x + (size_t)(tok0 + srow) * DDIM + skq * 8;

  const int fr_row = lane & 15;
  const int fr_s   = lane >> 4;
  const ushort* wf = &g_wf[0][0][0][0][0];
  const int b0 = ct * 16384 + lane * 8;   // wave's col-tile, product h
  #define PS 131072
  const int abase = tg * 8192;            // this wave's tg region offset

  f32x4 acc = {0.f, 0.f, 0.f, 0.f};

  float4 xa0, xa1, xb0, xb1;

  #define SPLIT_PHASE(X0, X1)                                             \
    {                                                                     \
      union BF8 { bf16x8 v; ushort u[8]; };                               \
      BF8 H, M, L;                                                        \
      const float av_[8] = {X0.x, X0.y, X0.z, X0.w, X1.x, X1.y, X1.z, X1.w}; \
      _Pragma("unroll")                                                   \
      for (int j = 0; j < 8; ++j) {                                       \
        ushort h_, m_, l_;                                                \
        split3(av_[j], h_, m_, l_);                                       \
        H.u[j] = h_; M.u[j] = m_; L.u[j] = l_;                            \
      }                                                                   \
      *(bf16x8*)(LA + stg * 8192 + so)         = H.v;                     \
      *(bf16x8*)(LA + 16384 + stg * 8192 + so) = M.v;                     \
      *(bf16x8*)(LA + 32768 + stg * 8192 + so) = L.v;                     \
    }

  #define MFMA_PHASE(ph)                                                  \
    _Pragma("unroll")                                                     \
    for (int c = 0; c < CPP; ++c) {                                       \
      int ro = c * 1024 + lane * 16;                                      \
      ro ^= ((ro >> 8) & 15) << 4;                                        \
      const bf16x8 Ah = *(const bf16x8*)(LA + abase + ro);                \
      const bf16x8 Am = *(const bf16x8*)(LA + 16384 + abase + ro);        \
      const bf16x8 Al = *(const bf16x8*)(LA + 32768 + abase + ro);        \
      const int co = ((ph) * CPP + c) * 512;                              \
      const bf16x8 Bh = *(const bf16x8*)&wf[b0 + co];                     \
      const bf16x8 Bm = *(const bf16x8*)&wf[b0 + PS + co];                \
      const bf16x8 Bl = *(const bf16x8*)&wf[b0 + 2 * PS + co];            \
      acc = __builtin_amdgcn_mfma_f32_16x16x32_bf16(Ah, Bh, acc, 0, 0, 0); \
      acc = __builtin_amdgcn_mfma_f32_16x16x32_bf16(Ah, Bm, acc, 0, 0, 0); \
      acc = __builtin_amdgcn_mfma_f32_16x16x32_bf16(Am, Bh, acc, 0, 0, 0); \
      acc = __builtin_amdgcn_mfma_f32_16x16x32_bf16(Ah, Bl, acc, 0, 0, 0); \
      acc = __builtin_amdgcn_mfma_f32_16x16x32_bf16(Al, Bh, acc, 0, 0, 0); \
      acc = __builtin_amdgcn_mfma_f32_16x16x32_bf16(Am, Bm, acc, 0, 0, 0); \
    }

  #define DO_PHASE(ph, C0, C1, N0, N1, PRE)                               \
    SPLIT_PHASE(C0, C1);                                                  \
    if (PRE) {                                                            \
      N0 = *(const float4*)&sx[(ph + 1) * 256];                           \
      N1 = *(const float4*)&sx[(ph + 1) * 256 + 4];                       \
    }                                                                     \
    __syncthreads();                                                      \
    MFMA_PHASE(ph);                                                       \
    __syncthreads();

  xa0 = *(const float4*)&sx[0];
  xa1 = *(const float4*)&sx[4];

  DO_PHASE(0, xa0, xa1, xb0, xb1, 1);
  DO_PHASE(1, xb0, xb1, xa0, xa1, 1);
  DO_PHASE(2, xa0, xa1, xb0, xb1, 1);
  DO_PHASE(3, xb0, xb1, xa0, xa1, 0);   // trailing barrier protects aliasing

  #undef DO_PHASE
  #undef SPLIT_PHASE
  #undef MFMA_PHASE
  #undef PS

  // ---- epilogue LDS aliases the x-stage buffer (all ldsA reads done) ----
  float (*lds_logits)[NCOL + 4] = (float (*)[NCOL + 4])LA;   // 16896 B
  float (*lps)[NEXP] = (float (*)[NEXP])(LA + 16896);        // 4096 B
  float (*lcb)[NEXP] = (float (*)[NEXP])(LA + 20992);        // 4096 B
  float* lspw        = (float*)(LA + 25088);                 // 64 B

  // C-write: D row = 4*(lane>>4)+r, col = lane&15 (m89-verified)
  #pragma unroll
  for (int r = 0; r < 4; ++r)
    lds_logits[tg * 16 + 4 * fr_s + r][ct * 16 + fr_row] = acc[r];
  __syncthreads();

  float* out_rw  = out;                        // [16384][2]
  float* out_idx = out + 2 * TOKENS;           // [16384][2]
  float* out_rp  = out + 4 * TOKENS + 1;       // [16384][64]

  float ps_acc = 0.0f, sp_acc = 0.0f, c_acc = 0.0f;

  for (int it = 0; it < 2; ++it) {
    const int tl = w * 2 + it;
    const int t  = tok0 + tl;
    const float cl = lds_logits[tl][lane];
    const float nl = lds_logits[tl][NEXP + lane];

    // router_probs = softmax(clean)
    const float m  = wave_max64(cl);
    const float v  = expf(cl - m);
    const float Z  = wave_sum64(v);
    const float rp = v / Z;
    out_rp[(size_t)t * NEXP + lane] = rp;
    ps_acc += rp;

    // noisy logits
    const float ns  = softplus_ref(nl);
    sp_acc += ns;
    const float noi = noise_normal((uint32_t)(t * NEXP + lane));
    const float lgn = __fadd_rn(cl, __fmul_rn(noi, ns));

    const float m2 = wave_max64(lgn);
    const float v2 = expf(lgn - m2);
    const float Z2 = wave_sum64(v2);
    const float p  = v2 / Z2;

    float p1; int i1;
    wave_argmax64(p, lane, p1, i1);
    const float pm = (lane == i1) ? -3.402823466e38f : p;
    float p2; int i2;
    wave_argmax64(pm, lane, p2, i2);

    c_acc += (float)((lane == i1) + (lane == i2));

    if (lane == 0) {
      const float s = p1 + p2;
      out_rw[t * 2 + 0]  = p1 / s;
      out_rw[t * 2 + 1]  = p2 / s;
      out_idx[t * 2 + 0] = (float)i1;
      out_idx[t * 2 + 1] = (float)i2;
    }
  }

  // block-level reduce, then one atomicAdd set per block
  lps[w][lane] = ps_acc;
  lcb[w][lane] = c_acc;
  const float spw = wave_sum64(sp_acc);
  if (lane == 0) lspw[w] = spw;
  __syncthreads();
  if (tid < NEXP) {
    float a = 0.0f, b = 0.0f;
    #pragma unroll
    for (int j = 0; j < 16; ++j) { a += lps[j][tid]; b += lcb[j][tid]; }
    atomicAdd(&g_ps[tid],  a);
    atomicAdd(&g_cnt[tid], b);
  }
  if (tid == 0) {
    float s = 0.0f;
    #pragma unroll
    for (int j = 0; j < 16; ++j) s += lspw[j];
    atomicAdd(&g_spa[0], s);
  }

  // ---- stage C: last-done block finalizes scalars (r3-proven pattern) ----
  __syncthreads();
  __shared__ int s_last;
  if (tid == 0) {
    __threadfence();           // release our accumulator adds device-wide
    const unsigned prev = __hip_atomic_fetch_add(&g_done, 1u, __ATOMIC_ACQ_REL,
                                                 __HIP_MEMORY_SCOPE_AGENT);
    s_last = (prev == (unsigned)(NBLK - 1)) ? 1 : 0;
  }
  __syncthreads();
  if (s_last) {
    if (tid < NEXP) {
      const float cnt = __hip_atomic_load(&g_cnt[tid], __ATOMIC_RELAXED,
                                          __HIP_MEMORY_SCOPE_AGENT);
      const float ps  = __hip_atomic_load(&g_ps[tid],  __ATOMIC_RELAXED,
                                          __HIP_MEMORY_SCOPE_AGENT);
      float term = (cnt / (float)TOKENS) * (ps / (float)TOKENS);
      #pragma unroll
      for (int off = 32; off; off >>= 1) term += __shfl_xor(term, off, 64);
      if (tid == 0) {
        out[4 * TOKENS] = 0.64f * term;   // LOAD_BALANCE_WEIGHT * NUM_EXPERTS
        const float spa = __hip_atomic_load(&g_spa[0], __ATOMIC_RELAXED,
                                            __HIP_MEMORY_SCOPE_AGENT);
        out[4 * TOKENS + 1 + TOKENS * NEXP] = spa / (float)(TOKENS * NEXP);
        // reset counters for the next graph replay
        __hip_atomic_store(&g_done, 0u, __ATOMIC_RELAXED, __HIP_MEMORY_SCOPE_AGENT);
        __hip_atomic_store(&g_wdone, 0u, __ATOMIC_RELAXED, __HIP_MEMORY_SCOPE_AGENT);
      }
    }
  }
}

// ---------------- host ----------------
extern "C" void kernel_launch(void* const* d_in, const int* in_sizes, int n_in,
                              void* d_out, int out_size, void* d_ws, size_t ws_size,
                              hipStream_t stream) {
  const float* x  = (const float*)d_in[0];   // f32 [4,4096,1024]
  const float* wg = (const float*)d_in[1];   // f32 [64,1024]
  const float* wn = (const float*)d_in[2];   // f32 [64,1024]
  float* out = (float*)d_out;                // f32, 1114114 elements

  (void)d_ws; (void)ws_size; (void)in_sizes; (void)n_in; (void)out_size;

  NoisyTopKRouter_57621281243491_kernel<<<NBLK, 1024, 0, stream>>>(x, wg, wn, out);
}

// Round 14
// 144.228 us; speedup vs baseline: 1.3105x; 1.3105x over previous
//
#include <hip/hip_runtime.h>
#include <stdint.h>

#define TOKENS 16384
#define DDIM   1024
#define NEXP   64
#define NCOL   128              // 64 gate + 64 noise cols
#define TB     32               // tokens per block
#define NBLK   (TOKENS / TB)    // 512 blocks
#define NCH    (DDIM / 32)      // 32 k-chunks of 32
#define NTILE  8                // 8 col-tiles of 16
#define CPP    8                // chunks per K-phase (4 phases x 256 k)

typedef __attribute__((ext_vector_type(8))) short bf16x8;  // 8 bf16 = 4 VGPR
typedef __attribute__((ext_vector_type(4))) float f32x4;

// -------- device-global scratch --------
// W pre-split, fragment order: g_wf[p][ct][kc][lane][j] =
//   W_p[ct*16+(lane&15)][kc*32+(lane>>4)*8+j]        (768 KB, L2-resident)
__device__ ushort g_wf[3][NTILE][NCH][64][8];
__device__ float g_ps[NEXP];          // sum of clean router probs per expert
__device__ float g_cnt[NEXP];         // top-2 counts per expert
__device__ float g_spa[1];            // sum of softplus

// ---------------- bf16 3-way split (x = h + m + l + O(2^-27 x)) ----------------
__device__ inline ushort bf16rne(float f) {
  uint32_t u = __float_as_uint(f);
  return (ushort)((u + 0x7fffu + ((u >> 16) & 1u)) >> 16);
}
__device__ inline float bf16tof(ushort h) {
  return __uint_as_float(((uint32_t)h) << 16);
}
__device__ inline void split3(float v, ushort& h, ushort& m, ushort& l) {
  h = bf16rne(v);
  float r1 = v - bf16tof(h);     // exact
  m = bf16rne(r1);
  float r2 = r1 - bf16tof(m);    // exact
  l = bf16rne(r2);
}

// ---------------- JAX threefry2x32 (20 rounds) ----------------
struct U2 { uint32_t a, b; };

__host__ __device__ constexpr U2 tf2x32(uint32_t k0, uint32_t k1,
                                        uint32_t x0, uint32_t x1) {
  uint32_t ks[3] = {k0, k1, k0 ^ k1 ^ 0x1BD11BDAu};
  const uint32_t rot[2][4] = {{13u, 15u, 26u, 6u}, {17u, 29u, 16u, 24u}};
  x0 += ks[0]; x1 += ks[1];
  for (int d = 0; d < 5; ++d) {
    for (int j = 0; j < 4; ++j) {
      uint32_t r = rot[d & 1][j];
      x0 += x1;
      x1 = (x1 << r) | (x1 >> (32u - r));
      x1 ^= x0;
    }
    x0 += ks[(d + 1) % 3];
    x1 += ks[(d + 2) % 3] + (uint32_t)(d + 1);
  }
  return U2{x0, x1};
}

// JAX >=0.5 partitionable threefry: bits[i] = xor-fold(tf(key, (0, i)))
__device__ inline uint32_t noise_bits(uint32_t i) {
  constexpr U2 NK = tf2x32(0u, 0u, 0u, 12345u);   // fold_in(key(0), 12345)
  U2 o = tf2x32(NK.a, NK.b, 0u, i);
  return o.a ^ o.b;
}

// XLA ErfInv32 (Giles polynomial)
__device__ inline float xla_erfinv(float x) {
  float w = -log1pf(-x * x);
  float p;
  if (w < 5.0f) {
    w = w - 2.5f;
    p = 2.81022636e-08f;
    p = 3.43273939e-07f + p * w;
    p = -3.5233877e-06f + p * w;
    p = -4.39150654e-06f + p * w;
    p = 0.00021858087f + p * w;
    p = -0.00125372503f + p * w;
    p = -0.00417768164f + p * w;
    p = 0.246640727f + p * w;
    p = 1.50140941f + p * w;
  } else {
    w = sqrtf(w) - 3.0f;
    p = -0.000200214257f;
    p = 0.000100950558f + p * w;
    p = 0.00134934322f + p * w;
    p = -0.00367342844f + p * w;
    p = 0.00573950773f + p * w;
    p = -0.0076224613f + p * w;
    p = 0.00943887047f + p * w;
    p = 1.00167406f + p * w;
    p = 2.83297682f + p * w;
  }
  return p * x;
}

__device__ inline float noise_normal(uint32_t i) {
  uint32_t bits = noise_bits(i);
  float f = __uint_as_float((bits >> 9) | 0x3f800000u) - 1.0f;  // [0,1)
  float u = f * 2.0f + (-0.99999994f);
  u = fmaxf(u, -0.99999994f);
  return 1.41421356237f * xla_erfinv(u);
}

__device__ inline float softplus_ref(float x) {
  return fmaxf(x, 0.0f) + log1pf(expf(-fabsf(x)));
}

// ---------------- wave(64) primitives ----------------
__device__ inline float wave_max64(float v) {
  #pragma unroll
  for (int off = 32; off; off >>= 1) v = fmaxf(v, __shfl_xor(v, off, 64));
  return v;
}
__device__ inline float wave_sum64(float v) {
  #pragma unroll
  for (int off = 32; off; off >>= 1) v += __shfl_xor(v, off, 64);
  return v;
}
__device__ inline void wave_argmax64(float v, int idx, float& mv, int& mi) {
  float bv = v; int bi = idx;
  #pragma unroll
  for (int off = 32; off; off >>= 1) {
    float ov = __shfl_xor(bv, off, 64);
    int   oi = __shfl_xor(bi, off, 64);
    if (ov > bv || (ov == bv && oi < bi)) { bv = ov; bi = oi; }
  }
  mv = bv; mi = bi;
}

// ---------------- K0: split W into fragment-ordered bf16 h/m/l ----------------
__global__ __launch_bounds__(64)
void wsplit_kernel(const float* __restrict__ wg, const float* __restrict__ wn) {
  const int ct   = blockIdx.x >> 5;      // col tile 0..7
  const int kc   = blockIdx.x & 31;      // k-chunk 0..31
  const int lane = threadIdx.x;          // 0..63
  const int col  = ct * 16 + (lane & 15);
  const int koff = kc * 32 + (lane >> 4) * 8;
  const float* src = (col < NEXP) ? (wg + (size_t)col * DDIM)
                                  : (wn + (size_t)(col - NEXP) * DDIM);
  const float4 v0 = *(const float4*)&src[koff];
  const float4 v1 = *(const float4*)&src[koff + 4];
  const float av[8] = {v0.x, v0.y, v0.z, v0.w, v1.x, v1.y, v1.z, v1.w};
  union BF8 { bf16x8 v; ushort u[8]; };
  BF8 H, M, L;
  #pragma unroll
  for (int j = 0; j < 8; ++j) {
    ushort h, m, l;
    split3(av[j], h, m, l);
    H.u[j] = h; M.u[j] = m; L.u[j] = l;
  }
  *(bf16x8*)&g_wf[0][ct][kc][lane][0] = H.v;
  *(bf16x8*)&g_wf[1][ct][kc][lane][0] = M.v;
  *(bf16x8*)&g_wf[2][ct][kc][lane][0] = L.v;

  if (blockIdx.x == 0) {   // zero loss accumulators (kernel boundary orders)
    g_ps[lane] = 0.0f; g_cnt[lane] = 0.0f;
    if (lane == 0) g_spa[0] = 0.0f;
  }
}

// phase barrier WITHOUT vmcnt drain: LDS writes must complete (lgkmcnt),
// but in-flight global loads (x prefetch -> private regs) legally span the
// barrier. hipcc's __syncthreads emits vmcnt(0) too -- that drain was the
// m97-style stall. "memory" clobbers fence compiler reordering both sides.
#define PHASE_BARRIER()                                      \
  asm volatile("s_waitcnt lgkmcnt(0)" ::: "memory");         \
  __builtin_amdgcn_s_barrier();                              \
  asm volatile("" ::: "memory");

// ---------------- K1: fused in-block x-split + MFMA GEMM + epilogue ----------------
// Structure identical to r12 (bit-identical math). Schedule-only changes:
// (1) phase barriers keep vmcnt outstanding (x prefetch spans barrier);
// (2) T5 s_setprio(1) around the MFMA cluster (phase role-split regime).
__global__ __launch_bounds__(1024, 8)
void NoisyTopKRouter_57621281243491_kernel(
    const float* __restrict__ x, float* __restrict__ out) {
  __shared__ ushort ldsA[3][2][CPP][64][8];     // 49.2 KB; epilogue aliases it

  const int tid  = threadIdx.x;
  const int w    = tid >> 6;          // wave 0..15
  const int lane = tid & 63;
  const int tg   = w & 1;             // token group
  const int ct   = w >> 1;            // col tile (pairs share -> L1 B reuse)
  const int tok0 = blockIdx.x * TB;

  char* LA = (char*)&ldsA[0][0][0][0][0];

  // ---- split-phase role: coalesced x read, swizzled fragment LDS write ----
  const int srow = tid >> 5;          // 0..31 token row
  const int skq  = tid & 31;          // 0..31: fragment (chunk, k-oct) in phase
  const int stg  = srow >> 4;         // token group
  const int sfr  = srow & 15;         // fragment row
  const int sc   = skq >> 2;          // chunk within phase (0..7)
  const int ss   = skq & 3;           // k-oct within chunk
  const int so   = (sc * 1024 + ss * 256 + sfr * 16) ^ ((skq & 15) << 4);
  const float* sx = x + (size_t)(tok0 + srow) * DDIM + skq * 8;

  // ---- MFMA role ----
  const int fr_row = lane & 15;
  const int fr_s   = lane >> 4;
  const ushort* wf = &g_wf[0][0][0][0][0];
  const int b0 = ct * 16384 + lane * 8;   // wave's col-tile, product h
  #define PS 131072
  const int abase = tg * 8192;            // this wave's tg region offset

  f32x4 acc = {0.f, 0.f, 0.f, 0.f};

  float4 xa0, xa1, xb0, xb1;

  #define SPLIT_PHASE(X0, X1)                                             \
    {                                                                     \
      union BF8 { bf16x8 v; ushort u[8]; };                               \
      BF8 H, M, L;                                                        \
      const float av_[8] = {X0.x, X0.y, X0.z, X0.w, X1.x, X1.y, X1.z, X1.w}; \
      _Pragma("unroll")                                                   \
      for (int j = 0; j < 8; ++j) {                                       \
        ushort h_, m_, l_;                                                \
        split3(av_[j], h_, m_, l_);                                       \
        H.u[j] = h_; M.u[j] = m_; L.u[j] = l_;                            \
      }                                                                   \
      *(bf16x8*)(LA + stg * 8192 + so)         = H.v;                     \
      *(bf16x8*)(LA + 16384 + stg * 8192 + so) = M.v;                     \
      *(bf16x8*)(LA + 32768 + stg * 8192 + so) = L.v;                     \
    }

  #define MFMA_PHASE(ph)                                                  \
    __builtin_amdgcn_s_setprio(1);                                        \
    _Pragma("unroll")                                                     \
    for (int c = 0; c < CPP; ++c) {                                       \
      int ro = c * 1024 + lane * 16;                                      \
      ro ^= ((ro >> 8) & 15) << 4;                                        \
      const bf16x8 Ah = *(const bf16x8*)(LA + abase + ro);                \
      const bf16x8 Am = *(const bf16x8*)(LA + 16384 + abase + ro);        \
      const bf16x8 Al = *(const bf16x8*)(LA + 32768 + abase + ro);        \
      const int co = ((ph) * CPP + c) * 512;                              \
      const bf16x8 Bh = *(const bf16x8*)&wf[b0 + co];                     \
      const bf16x8 Bm = *(const bf16x8*)&wf[b0 + PS + co];                \
      const bf16x8 Bl = *(const bf16x8*)&wf[b0 + 2 * PS + co];            \
      acc = __builtin_amdgcn_mfma_f32_16x16x32_bf16(Ah, Bh, acc, 0, 0, 0); \
      acc = __builtin_amdgcn_mfma_f32_16x16x32_bf16(Ah, Bm, acc, 0, 0, 0); \
      acc = __builtin_amdgcn_mfma_f32_16x16x32_bf16(Am, Bh, acc, 0, 0, 0); \
      acc = __builtin_amdgcn_mfma_f32_16x16x32_bf16(Ah, Bl, acc, 0, 0, 0); \
      acc = __builtin_amdgcn_mfma_f32_16x16x32_bf16(Al, Bh, acc, 0, 0, 0); \
      acc = __builtin_amdgcn_mfma_f32_16x16x32_bf16(Am, Bm, acc, 0, 0, 0); \
    }                                                                     \
    __builtin_amdgcn_s_setprio(0);

  // phase ph: split cur regs, prefetch ph+1 (loads stay in flight across
  // the barrier -- no vmcnt drain), barrier, MFMA, barrier
  #define DO_PHASE(ph, C0, C1, N0, N1, PRE)                               \
    SPLIT_PHASE(C0, C1);                                                  \
    if (PRE) {                                                            \
      N0 = *(const float4*)&sx[(ph + 1) * 256];                           \
      N1 = *(const float4*)&sx[(ph + 1) * 256 + 4];                       \
    }                                                                     \
    PHASE_BARRIER();                                                      \
    MFMA_PHASE(ph);                                                       \
    PHASE_BARRIER();

  // prologue
  xa0 = *(const float4*)&sx[0];
  xa1 = *(const float4*)&sx[4];

  DO_PHASE(0, xa0, xa1, xb0, xb1, 1);
  DO_PHASE(1, xb0, xb1, xa0, xa1, 1);
  DO_PHASE(2, xa0, xa1, xb0, xb1, 1);
  DO_PHASE(3, xb0, xb1, xa0, xa1, 0);   // trailing barrier protects aliasing

  #undef DO_PHASE
  #undef SPLIT_PHASE
  #undef MFMA_PHASE
  #undef PS

  // ---- epilogue LDS aliases the x-stage buffer (all ldsA reads done) ----
  float (*lds_logits)[NCOL + 4] = (float (*)[NCOL + 4])LA;   // 16896 B
  float (*lps)[NEXP] = (float (*)[NEXP])(LA + 16896);        // 4096 B
  float (*lcb)[NEXP] = (float (*)[NEXP])(LA + 20992);        // 4096 B
  float* lspw        = (float*)(LA + 25088);                 // 64 B

  // C-write: D row = 4*(lane>>4)+r, col = lane&15 (m89-verified)
  #pragma unroll
  for (int r = 0; r < 4; ++r)
    lds_logits[tg * 16 + 4 * fr_s + r][ct * 16 + fr_row] = acc[r];
  __syncthreads();

  // ---- epilogue: 2 tokens per wave, lane = expert (identical to r1 K2 math) ----
  float* out_rw  = out;                        // [16384][2]
  float* out_idx = out + 2 * TOKENS;           // [16384][2]
  float* out_rp  = out + 4 * TOKENS + 1;       // [16384][64]

  float ps_acc = 0.0f, sp_acc = 0.0f, c_acc = 0.0f;

  for (int it = 0; it < 2; ++it) {
    const int tl = w * 2 + it;
    const int t  = tok0 + tl;
    const float cl = lds_logits[tl][lane];
    const float nl = lds_logits[tl][NEXP + lane];

    // router_probs = softmax(clean)
    const float m  = wave_max64(cl);
    const float v  = expf(cl - m);
    const float Z  = wave_sum64(v);
    const float rp = v / Z;
    out_rp[(size_t)t * NEXP + lane] = rp;
    ps_acc += rp;

    // noisy logits
    const float ns  = softplus_ref(nl);
    sp_acc += ns;
    const float noi = noise_normal((uint32_t)(t * NEXP + lane));
    const float lgn = __fadd_rn(cl, __fmul_rn(noi, ns));

    const float m2 = wave_max64(lgn);
    const float v2 = expf(lgn - m2);
    const float Z2 = wave_sum64(v2);
    const float p  = v2 / Z2;

    float p1; int i1;
    wave_argmax64(p, lane, p1, i1);
    const float pm = (lane == i1) ? -3.402823466e38f : p;
    float p2; int i2;
    wave_argmax64(pm, lane, p2, i2);

    c_acc += (float)((lane == i1) + (lane == i2));

    if (lane == 0) {
      const float s = p1 + p2;
      out_rw[t * 2 + 0]  = p1 / s;
      out_rw[t * 2 + 1]  = p2 / s;
      out_idx[t * 2 + 0] = (float)i1;
      out_idx[t * 2 + 1] = (float)i2;
    }
  }

  // block-level reduce, then one atomicAdd set per block
  lps[w][lane] = ps_acc;
  lcb[w][lane] = c_acc;
  const float spw = wave_sum64(sp_acc);
  if (lane == 0) lspw[w] = spw;
  __syncthreads();
  if (tid < NEXP) {
    float a = 0.0f, b = 0.0f;
    #pragma unroll
    for (int j = 0; j < 16; ++j) { a += lps[j][tid]; b += lcb[j][tid]; }
    atomicAdd(&g_ps[tid],  a);
    atomicAdd(&g_cnt[tid], b);
  }
  if (tid == 0) {
    float s = 0.0f;
    #pragma unroll
    for (int j = 0; j < 16; ++j) s += lspw[j];
    atomicAdd(&g_spa[0], s);
  }
}

// ---------------- K3: finalize scalars ----------------
__global__ void finalize_kernel(float* __restrict__ out) {
  const int lane = threadIdx.x;
  float term = (g_cnt[lane] / (float)TOKENS) * (g_ps[lane] / (float)TOKENS);
  #pragma unroll
  for (int off = 32; off; off >>= 1) term += __shfl_xor(term, off, 64);
  if (lane == 0) {
    out[4 * TOKENS] = 0.64f * term;   // LOAD_BALANCE_WEIGHT * NUM_EXPERTS
    out[4 * TOKENS + 1 + TOKENS * NEXP] = g_spa[0] / (float)(TOKENS * NEXP);
  }
}

// ---------------- host ----------------
extern "C" void kernel_launch(void* const* d_in, const int* in_sizes, int n_in,
                              void* d_out, int out_size, void* d_ws, size_t ws_size,
                              hipStream_t stream) {
  const float* x  = (const float*)d_in[0];   // f32 [4,4096,1024]
  const float* wg = (const float*)d_in[1];   // f32 [64,1024]
  const float* wn = (const float*)d_in[2];   // f32 [64,1024]
  float* out = (float*)d_out;                // f32, 1114114 elements

  (void)d_ws; (void)ws_size; (void)in_sizes; (void)n_in; (void)out_size;

  wsplit_kernel<<<NTILE * NCH, 64, 0, stream>>>(wg, wn);
  NoisyTopKRouter_57621281243491_kernel<<<NBLK, 1024, 0, stream>>>(x, out);
  finalize_kernel<<<1, 64, 0, stream>>>(out);
}

// Round 15
// 138.327 us; speedup vs baseline: 1.3664x; 1.0427x over previous
//
#include <hip/hip_runtime.h>
#include <stdint.h>

#define TOKENS 16384
#define DDIM   1024
#define NEXP   64
#define NCOL   128              // 64 gate + 64 noise cols
#define TB     64               // tokens per block (halves B L2 traffic vs 32)
#define NBLK   (TOKENS / TB)    // 256 blocks
#define NCH    (DDIM / 32)      // 32 k-chunks of 32
#define NTILE  8                // 8 col-tiles of 16
#define CPP    4                // chunks per K-phase (8 phases x 128 k)

typedef __attribute__((ext_vector_type(8))) short bf16x8;  // 8 bf16 = 4 VGPR
typedef __attribute__((ext_vector_type(4))) float f32x4;

// -------- device-global scratch --------
// W pre-split, fragment order: g_wf[p][ct][kc][lane][j] =
//   W_p[ct*16+(lane&15)][kc*32+(lane>>4)*8+j]        (768 KB, L2-resident)
__device__ ushort g_wf[3][NTILE][NCH][64][8];
__device__ float g_ps[NEXP];          // sum of clean router probs per expert
__device__ float g_cnt[NEXP];         // top-2 counts per expert
__device__ float g_spa[1];            // sum of softplus

// ---------------- bf16 3-way split (x = h + m + l + O(2^-27 x)) ----------------
__device__ inline ushort bf16rne(float f) {
  uint32_t u = __float_as_uint(f);
  return (ushort)((u + 0x7fffu + ((u >> 16) & 1u)) >> 16);
}
__device__ inline float bf16tof(ushort h) {
  return __uint_as_float(((uint32_t)h) << 16);
}
__device__ inline void split3(float v, ushort& h, ushort& m, ushort& l) {
  h = bf16rne(v);
  float r1 = v - bf16tof(h);     // exact
  m = bf16rne(r1);
  float r2 = r1 - bf16tof(m);    // exact
  l = bf16rne(r2);
}

// ---------------- JAX threefry2x32 (20 rounds) ----------------
struct U2 { uint32_t a, b; };

__host__ __device__ constexpr U2 tf2x32(uint32_t k0, uint32_t k1,
                                        uint32_t x0, uint32_t x1) {
  uint32_t ks[3] = {k0, k1, k0 ^ k1 ^ 0x1BD11BDAu};
  const uint32_t rot[2][4] = {{13u, 15u, 26u, 6u}, {17u, 29u, 16u, 24u}};
  x0 += ks[0]; x1 += ks[1];
  for (int d = 0; d < 5; ++d) {
    for (int j = 0; j < 4; ++j) {
      uint32_t r = rot[d & 1][j];
      x0 += x1;
      x1 = (x1 << r) | (x1 >> (32u - r));
      x1 ^= x0;
    }
    x0 += ks[(d + 1) % 3];
    x1 += ks[(d + 2) % 3] + (uint32_t)(d + 1);
  }
  return U2{x0, x1};
}

// JAX >=0.5 partitionable threefry: bits[i] = xor-fold(tf(key, (0, i)))
__device__ inline uint32_t noise_bits(uint32_t i) {
  constexpr U2 NK = tf2x32(0u, 0u, 0u, 12345u);   // fold_in(key(0), 12345)
  U2 o = tf2x32(NK.a, NK.b, 0u, i);
  return o.a ^ o.b;
}

// XLA ErfInv32 (Giles polynomial)
__device__ inline float xla_erfinv(float x) {
  float w = -log1pf(-x * x);
  float p;
  if (w < 5.0f) {
    w = w - 2.5f;
    p = 2.81022636e-08f;
    p = 3.43273939e-07f + p * w;
    p = -3.5233877e-06f + p * w;
    p = -4.39150654e-06f + p * w;
    p = 0.00021858087f + p * w;
    p = -0.00125372503f + p * w;
    p = -0.00417768164f + p * w;
    p = 0.246640727f + p * w;
    p = 1.50140941f + p * w;
  } else {
    w = sqrtf(w) - 3.0f;
    p = -0.000200214257f;
    p = 0.000100950558f + p * w;
    p = 0.00134934322f + p * w;
    p = -0.00367342844f + p * w;
    p = 0.00573950773f + p * w;
    p = -0.0076224613f + p * w;
    p = 0.00943887047f + p * w;
    p = 1.00167406f + p * w;
    p = 2.83297682f + p * w;
  }
  return p * x;
}

__device__ inline float noise_normal(uint32_t i) {
  uint32_t bits = noise_bits(i);
  float f = __uint_as_float((bits >> 9) | 0x3f800000u) - 1.0f;  // [0,1)
  float u = f * 2.0f + (-0.99999994f);
  u = fmaxf(u, -0.99999994f);
  return 1.41421356237f * xla_erfinv(u);
}

__device__ inline float softplus_ref(float x) {
  return fmaxf(x, 0.0f) + log1pf(expf(-fabsf(x)));
}

// ---------------- wave(64) primitives ----------------
__device__ inline float wave_max64(float v) {
  #pragma unroll
  for (int off = 32; off; off >>= 1) v = fmaxf(v, __shfl_xor(v, off, 64));
  return v;
}
__device__ inline float wave_sum64(float v) {
  #pragma unroll
  for (int off = 32; off; off >>= 1) v += __shfl_xor(v, off, 64);
  return v;
}
__device__ inline void wave_argmax64(float v, int idx, float& mv, int& mi) {
  float bv = v; int bi = idx;
  #pragma unroll
  for (int off = 32; off; off >>= 1) {
    float ov = __shfl_xor(bv, off, 64);
    int   oi = __shfl_xor(bi, off, 64);
    if (ov > bv || (ov == bv && oi < bi)) { bv = ov; bi = oi; }
  }
  mv = bv; mi = bi;
}

// ---------------- K0: split W into fragment-ordered bf16 h/m/l ----------------
__global__ __launch_bounds__(64)
void wsplit_kernel(const float* __restrict__ wg, const float* __restrict__ wn) {
  const int ct   = blockIdx.x >> 5;      // col tile 0..7
  const int kc   = blockIdx.x & 31;      // k-chunk 0..31
  const int lane = threadIdx.x;          // 0..63
  const int col  = ct * 16 + (lane & 15);
  const int koff = kc * 32 + (lane >> 4) * 8;
  const float* src = (col < NEXP) ? (wg + (size_t)col * DDIM)
                                  : (wn + (size_t)(col - NEXP) * DDIM);
  const float4 v0 = *(const float4*)&src[koff];
  const float4 v1 = *(const float4*)&src[koff + 4];
  const float av[8] = {v0.x, v0.y, v0.z, v0.w, v1.x, v1.y, v1.z, v1.w};
  union BF8 { bf16x8 v; ushort u[8]; };
  BF8 H, M, L;
  #pragma unroll
  for (int j = 0; j < 8; ++j) {
    ushort h, m, l;
    split3(av[j], h, m, l);
    H.u[j] = h; M.u[j] = m; L.u[j] = l;
  }
  *(bf16x8*)&g_wf[0][ct][kc][lane][0] = H.v;
  *(bf16x8*)&g_wf[1][ct][kc][lane][0] = M.v;
  *(bf16x8*)&g_wf[2][ct][kc][lane][0] = L.v;

  if (blockIdx.x == 0) {   // zero loss accumulators (kernel boundary orders)
    g_ps[lane] = 0.0f; g_cnt[lane] = 0.0f;
    if (lane == 0) g_spa[0] = 0.0f;
  }
}

// phase barrier without vmcnt drain (r14-verified correct)
#define PHASE_BARRIER()                                      \
  asm volatile("s_waitcnt lgkmcnt(0)" ::: "memory");         \
  __builtin_amdgcn_s_barrier();                              \
  asm volatile("" ::: "memory");

// ---------------- K1: fused in-block x-split + MFMA GEMM + epilogue ----------------
// TB=64, grid 256: halves B L2 traffic (393->196 MB) and halves per-MFMA
// address VALU (3 B loads now feed 12 MFMAs). 16 waves = 8 ct x 2 tg-pairs;
// wave owns one col-tile and TWO 16-token groups (2 static f32x4 accs).
// 8 K-phases of 128: {split x into swizzled fragment LDS -> barrier ->
// 4 chunks x (6 ds_read + 3 B-loads + 12 MFMA) -> barrier}. LDS 49.2 KB,
// 1 block/CU (grid-capped), 4 waves/SIMD -- r11/r12 proved occupancy
// regime is non-binding. launch_bounds(1024,4): 128-VGPR pipelining room.
// Per-output chunk order (kc 0..31) + 6-product order unchanged from
// r5-r14 -> bit-identical logits.
__global__ __launch_bounds__(1024, 4)
void NoisyTopKRouter_57621281243491_kernel(
    const float* __restrict__ x, float* __restrict__ out) {
  __shared__ ushort ldsA[3][4][CPP][64][8];     // 49.2 KB; epilogue aliases it

  const int tid  = threadIdx.x;
  const int w    = tid >> 6;          // wave 0..15
  const int lane = tid & 63;
  const int ct   = w >> 1;            // col tile 0..7
  const int tgp  = w & 1;             // tg pair: handles tg {2*tgp, 2*tgp+1}
  const int tok0 = blockIdx.x * TB;

  char* LA = (char*)&ldsA[0][0][0][0][0];

  // ---- split-phase role: coalesced x read, swizzled fragment LDS write ----
  const int srow = tid >> 4;          // 0..63 token row
  const int skq  = tid & 15;          // 0..15: fragment (chunk, k-oct) in phase
  const int stg  = srow >> 4;         // token group 0..3
  const int sfr  = srow & 15;         // fragment row
  const int sc   = skq >> 2;          // chunk within phase (0..3)
  const int ss   = skq & 3;           // k-oct within chunk
  // byte offset within a (product, tg) 4 KB region; XOR matches read side
  const int so   = (sc * 1024 + ss * 256 + sfr * 16) ^ ((skq & 15) << 4);
  const float* sx = x + (size_t)(tok0 + srow) * DDIM + skq * 8;

  // ---- MFMA role ----
  const int fr_row = lane & 15;
  const int fr_s   = lane >> 4;
  const ushort* wf = &g_wf[0][0][0][0][0];
  const int b0 = ct * 16384 + lane * 8;   // wave's col-tile, product h
  #define PS 131072
  const int abA = (tgp * 2) * 4096;       // tg region A (bytes)
  const int abB = abA + 4096;             // tg region B

  f32x4 accA = {0.f, 0.f, 0.f, 0.f};
  f32x4 accB = {0.f, 0.f, 0.f, 0.f};

  float4 xa0, xa1, xb0, xb1;

  #define SPLIT_PHASE(X0, X1)                                             \
    {                                                                     \
      union BF8 { bf16x8 v; ushort u[8]; };                               \
      BF8 H, M, L;                                                        \
      const float av_[8] = {X0.x, X0.y, X0.z, X0.w, X1.x, X1.y, X1.z, X1.w}; \
      _Pragma("unroll")                                                   \
      for (int j = 0; j < 8; ++j) {                                       \
        ushort h_, m_, l_;                                                \
        split3(av_[j], h_, m_, l_);                                       \
        H.u[j] = h_; M.u[j] = m_; L.u[j] = l_;                            \
      }                                                                   \
      *(bf16x8*)(LA + stg * 4096 + so)         = H.v;                     \
      *(bf16x8*)(LA + 16384 + stg * 4096 + so) = M.v;                     \
      *(bf16x8*)(LA + 32768 + stg * 4096 + so) = L.v;                     \
    }

  #define MFMA_PHASE(ph)                                                  \
    __builtin_amdgcn_s_setprio(1);                                        \
    _Pragma("unroll")                                                     \
    for (int c = 0; c < CPP; ++c) {                                       \
      int ro = c * 1024 + lane * 16;                                      \
      ro ^= ((ro >> 8) & 15) << 4;                                        \
      const bf16x8 AhA = *(const bf16x8*)(LA + abA + ro);                 \
      const bf16x8 AmA = *(const bf16x8*)(LA + 16384 + abA + ro);         \
      const bf16x8 AlA = *(const bf16x8*)(LA + 32768 + abA + ro);         \
      const bf16x8 AhB = *(const bf16x8*)(LA + abB + ro);                 \
      const bf16x8 AmB = *(const bf16x8*)(LA + 16384 + abB + ro);         \
      const bf16x8 AlB = *(const bf16x8*)(LA + 32768 + abB + ro);         \
      const int co = ((ph) * CPP + c) * 512;                              \
      const bf16x8 Bh = *(const bf16x8*)&wf[b0 + co];                     \
      const bf16x8 Bm = *(const bf16x8*)&wf[b0 + PS + co];                \
      const bf16x8 Bl = *(const bf16x8*)&wf[b0 + 2 * PS + co];            \
      accA = __builtin_amdgcn_mfma_f32_16x16x32_bf16(AhA, Bh, accA, 0, 0, 0); \
      accA = __builtin_amdgcn_mfma_f32_16x16x32_bf16(AhA, Bm, accA, 0, 0, 0); \
      accA = __builtin_amdgcn_mfma_f32_16x16x32_bf16(AmA, Bh, accA, 0, 0, 0); \
      accA = __builtin_amdgcn_mfma_f32_16x16x32_bf16(AhA, Bl, accA, 0, 0, 0); \
      accA = __builtin_amdgcn_mfma_f32_16x16x32_bf16(AlA, Bh, accA, 0, 0, 0); \
      accA = __builtin_amdgcn_mfma_f32_16x16x32_bf16(AmA, Bm, accA, 0, 0, 0); \
      accB = __builtin_amdgcn_mfma_f32_16x16x32_bf16(AhB, Bh, accB, 0, 0, 0); \
      accB = __builtin_amdgcn_mfma_f32_16x16x32_bf16(AhB, Bm, accB, 0, 0, 0); \
      accB = __builtin_amdgcn_mfma_f32_16x16x32_bf16(AmB, Bh, accB, 0, 0, 0); \
      accB = __builtin_amdgcn_mfma_f32_16x16x32_bf16(AhB, Bl, accB, 0, 0, 0); \
      accB = __builtin_amdgcn_mfma_f32_16x16x32_bf16(AlB, Bh, accB, 0, 0, 0); \
      accB = __builtin_amdgcn_mfma_f32_16x16x32_bf16(AmB, Bm, accB, 0, 0, 0); \
    }                                                                     \
    __builtin_amdgcn_s_setprio(0);

  // phase ph: split cur regs, prefetch ph+1 (stays in flight across the
  // barrier -- no vmcnt drain), barrier, MFMA, barrier
  #define DO_PHASE(ph, C0, C1, N0, N1, PRE)                               \
    SPLIT_PHASE(C0, C1);                                                  \
    if (PRE) {                                                            \
      N0 = *(const float4*)&sx[(ph + 1) * 128];                           \
      N1 = *(const float4*)&sx[(ph + 1) * 128 + 4];                       \
    }                                                                     \
    PHASE_BARRIER();                                                      \
    MFMA_PHASE(ph);                                                       \
    PHASE_BARRIER();

  // prologue
  xa0 = *(const float4*)&sx[0];
  xa1 = *(const float4*)&sx[4];

  DO_PHASE(0, xa0, xa1, xb0, xb1, 1);
  DO_PHASE(1, xb0, xb1, xa0, xa1, 1);
  DO_PHASE(2, xa0, xa1, xb0, xb1, 1);
  DO_PHASE(3, xb0, xb1, xa0, xa1, 1);
  DO_PHASE(4, xa0, xa1, xb0, xb1, 1);
  DO_PHASE(5, xb0, xb1, xa0, xa1, 1);
  DO_PHASE(6, xa0, xa1, xb0, xb1, 1);
  DO_PHASE(7, xb0, xb1, xa0, xa1, 0);   // trailing barrier protects aliasing

  #undef DO_PHASE
  #undef SPLIT_PHASE
  #undef MFMA_PHASE
  #undef PS

  // ---- epilogue LDS aliases the x-stage buffer (all ldsA reads done) ----
  float (*lds_logits)[NCOL + 4] = (float (*)[NCOL + 4])LA;   // 33792 B
  float (*lps)[NEXP] = (float (*)[NEXP])(LA + 33792);        // 4096 B
  float (*lcb)[NEXP] = (float (*)[NEXP])(LA + 37888);        // 4096 B
  float* lspw        = (float*)(LA + 41984);                 // 64 B

  // C-write: D row = 4*(lane>>4)+r, col = lane&15 (m89-verified)
  #pragma unroll
  for (int r = 0; r < 4; ++r) {
    lds_logits[(tgp * 2) * 16 + 4 * fr_s + r][ct * 16 + fr_row]     = accA[r];
    lds_logits[(tgp * 2 + 1) * 16 + 4 * fr_s + r][ct * 16 + fr_row] = accB[r];
  }
  __syncthreads();

  // ---- epilogue: 4 tokens per wave, lane = expert (identical to r1 K2 math) ----
  float* out_rw  = out;                        // [16384][2]
  float* out_idx = out + 2 * TOKENS;           // [16384][2]
  float* out_rp  = out + 4 * TOKENS + 1;       // [16384][64]

  float ps_acc = 0.0f, sp_acc = 0.0f, c_acc = 0.0f;

  for (int it = 0; it < 4; ++it) {
    const int tl = w * 4 + it;
    const int t  = tok0 + tl;
    const float cl = lds_logits[tl][lane];
    const float nl = lds_logits[tl][NEXP + lane];

    // router_probs = softmax(clean)
    const float m  = wave_max64(cl);
    const float v  = expf(cl - m);
    const float Z  = wave_sum64(v);
    const float rp = v / Z;
    out_rp[(size_t)t * NEXP + lane] = rp;
    ps_acc += rp;

    // noisy logits
    const float ns  = softplus_ref(nl);
    sp_acc += ns;
    const float noi = noise_normal((uint32_t)(t * NEXP + lane));
    const float lgn = __fadd_rn(cl, __fmul_rn(noi, ns));

    const float m2 = wave_max64(lgn);
    const float v2 = expf(lgn - m2);
    const float Z2 = wave_sum64(v2);
    const float p  = v2 / Z2;

    float p1; int i1;
    wave_argmax64(p, lane, p1, i1);
    const float pm = (lane == i1) ? -3.402823466e38f : p;
    float p2; int i2;
    wave_argmax64(pm, lane, p2, i2);

    c_acc += (float)((lane == i1) + (lane == i2));

    if (lane == 0) {
      const float s = p1 + p2;
      out_rw[t * 2 + 0]  = p1 / s;
      out_rw[t * 2 + 1]  = p2 / s;
      out_idx[t * 2 + 0] = (float)i1;
      out_idx[t * 2 + 1] = (float)i2;
    }
  }

  // block-level reduce, then one atomicAdd set per block
  lps[w][lane] = ps_acc;
  lcb[w][lane] = c_acc;
  const float spw = wave_sum64(sp_acc);
  if (lane == 0) lspw[w] = spw;
  __syncthreads();
  if (tid < NEXP) {
    float a = 0.0f, b = 0.0f;
    #pragma unroll
    for (int j = 0; j < 16; ++j) { a += lps[j][tid]; b += lcb[j][tid]; }
    atomicAdd(&g_ps[tid],  a);
    atomicAdd(&g_cnt[tid], b);
  }
  if (tid == 0) {
    float s = 0.0f;
    #pragma unroll
    for (int j = 0; j < 16; ++j) s += lspw[j];
    atomicAdd(&g_spa[0], s);
  }
}

// ---------------- K3: finalize scalars ----------------
__global__ void finalize_kernel(float* __restrict__ out) {
  const int lane = threadIdx.x;
  float term = (g_cnt[lane] / (float)TOKENS) * (g_ps[lane] / (float)TOKENS);
  #pragma unroll
  for (int off = 32; off; off >>= 1) term += __shfl_xor(term, off, 64);
  if (lane == 0) {
    out[4 * TOKENS] = 0.64f * term;   // LOAD_BALANCE_WEIGHT * NUM_EXPERTS
    out[4 * TOKENS + 1 + TOKENS * NEXP] = g_spa[0] / (float)(TOKENS * NEXP);
  }
}

// ---------------- host ----------------
extern "C" void kernel_launch(void* const* d_in, const int* in_sizes, int n_in,
                              void* d_out, int out_size, void* d_ws, size_t ws_size,
                              hipStream_t stream) {
  const float* x  = (const float*)d_in[0];   // f32 [4,4096,1024]
  const float* wg = (const float*)d_in[1];   // f32 [64,1024]
  const float* wn = (const float*)d_in[2];   // f32 [64,1024]
  float* out = (float*)d_out;                // f32, 1114114 elements

  (void)d_ws; (void)ws_size; (void)in_sizes; (void)n_in; (void)out_size;

  wsplit_kernel<<<NTILE * NCH, 64, 0, stream>>>(wg, wn);
  NoisyTopKRouter_57621281243491_kernel<<<NBLK, 1024, 0, stream>>>(x, out);
  finalize_kernel<<<1, 64, 0, stream>>>(out);
}